// Round 6
// baseline (103.937 us; speedup 1.0000x reference)
//
#include <hip/hip_runtime.h>
#include <hip/hip_bf16.h>
#include <hip/hip_fp16.h>

#define NB 4
#define NS 2048
#define NE 128
#define NH 16
#define ND 8

#define THALF 1024     // t rows staged per phase (2 phases)
#define NCH 32         // chunks of 32 t per phase
#define VSTRIDE 1032   // LDS vT row stride (shorts): 16B-aligned, 4-bank stagger/row
#define VGSTR 2056     // global vT row stride (shorts): 2048 + 8 pad, 16B-aligned

typedef __attribute__((ext_vector_type(8))) _Float16 half8;
typedef __attribute__((ext_vector_type(4))) _Float16 half4;
typedef __attribute__((ext_vector_type(4))) float f32x4;

__device__ __forceinline__ unsigned int pkrtz(float a, float b) {
    typedef __fp16 fp16v2 __attribute__((ext_vector_type(2)));
    union { fp16v2 h; unsigned int u; } v;
    v.h = __builtin_amdgcn_cvt_pkrtz(a, b);
    return v.u;
}
__device__ __forceinline__ unsigned short f2h(float a) {
    return __half_as_ushort(__float2half(a));   // RNE
}
__device__ __forceinline__ half8 mk_half8(unsigned u0, unsigned u1,
                                          unsigned u2, unsigned u3) {
    union { half8 h; unsigned u[4]; } v;
    v.u[0] = u0; v.u[1] = u1; v.u[2] = u2; v.u[3] = u3;
    return v.h;
}

// cumprod-of-cos row: p[d] = prod_{i<=d} cos(x[i] + th[i])
__device__ __forceinline__ void qrow(const float* __restrict__ xp,
                                     const float* th, float* p) {
    float4 a = *(const float4*)xp, c = *(const float4*)(xp + 4);
    float t = 1.f;
    t *= cosf(a.x + th[0]); p[0] = t;
    t *= cosf(a.y + th[1]); p[1] = t;
    t *= cosf(a.z + th[2]); p[2] = t;
    t *= cosf(a.w + th[3]); p[3] = t;
    t *= cosf(c.x + th[4]); p[4] = t;
    t *= cosf(c.y + th[5]); p[5] = t;
    t *= cosf(c.z + th[6]); p[6] = t;
    t *= cosf(c.w + th[7]); p[7] = t;
}

// R13 qgen: gid remap for WRITE coalescing. Old mapping put adjacent lanes on
// adjacent h -> the two uint4 qg stores per lane were 32 KB apart (64 VMEM
// segments/instr) and the 9 vtg dword stores were pure 4B scatter. Now
// bh = gid>>10, j = gid&1023: adjacent lanes = adjacent s for one (b,h) ->
// qg stores are 512B-contiguous per 16-lane group, vtg dwords cluster into
// 64B windows. x reads become 1KB-strided 32B loads (uncoalesced) but x is
// 4 MB and L2/L3-absorbed — writes were the expensive side.
// Block 0 additionally converts w -> wf16 once (proj is now LDS-free).
__global__ __launch_bounds__(256) void qgen_kernel(
        const float* __restrict__ x,
        const float* __restrict__ theta,
        const int* __restrict__ mask,
        const float* __restrict__ w,
        unsigned short* __restrict__ qg,
        unsigned short* __restrict__ vtg,
        unsigned short* __restrict__ wf16) {
    const int gid = blockIdx.x * 256 + threadIdx.x;   // 0..65535
    const int bh = gid >> 10;           // (b,h), 0..63
    const int b = bh >> 4, h = bh & (NH - 1);
    const int j = gid & 1023;           // pair within (b,h)
    const int s0 = 2 * j;
    const float SC = 0.71421629f;       // sqrt(log2(e)/sqrt(8))

    if (blockIdx.x == 0) {              // one-time w -> f16 (row-major [n][k])
        for (int i = threadIdx.x; i < 2048; i += 256) {
            const float* wp = w + i * 8;
            float4 a = *(const float4*)wp, c = *(const float4*)(wp + 4);
            uint4 pk;
            pk.x = pkrtz(a.x, a.y); pk.y = pkrtz(a.z, a.w);
            pk.z = pkrtz(c.x, c.y); pk.w = pkrtz(c.z, c.w);
            *(uint4*)&wf16[i * 8] = pk;
        }
    }

    float th[ND];
#pragma unroll
    for (int d = 0; d < ND; d++) th[d] = theta[d];

    float p0[ND], p1[ND];
    qrow(x + ((size_t)(b * NS + s0) * NE + h * ND), th, p0);
    qrow(x + ((size_t)(b * NS + s0 + 1) * NE + h * ND), th, p1);
    const float mz0 = mask[b * NS + s0] ? 1.f : 0.f;
    const float mz1 = mask[b * NS + s0 + 1] ? 1.f : 0.f;

    uint4 qa, qb;
    qa.x = pkrtz(p0[0] * SC, p0[1] * SC);
    qa.y = pkrtz(p0[2] * SC, p0[3] * SC);
    qa.z = pkrtz(p0[4] * SC, p0[5] * SC);
    qa.w = pkrtz(p0[6] * SC, p0[7] * SC);
    qb.x = pkrtz(p1[0] * SC, p1[1] * SC);
    qb.y = pkrtz(p1[2] * SC, p1[3] * SC);
    qb.z = pkrtz(p1[4] * SC, p1[5] * SC);
    qb.w = pkrtz(p1[6] * SC, p1[7] * SC);
    *(uint4*)&qg[((size_t)bh * NS + s0) * ND] = qa;
    *(uint4*)&qg[((size_t)bh * NS + s0 + 1) * ND] = qb;

    // pi position within this half: ta = 4*(i>>2)+2*(i&1)+16*((i>>1)&1) inverted
    const int H = s0 >> 10, r0 = s0 & 1023;
    const int chs = r0 >> 5, u = (r0 & 31) >> 1;
    const int i = (u & 1) | (((u >> 3) & 1) << 1) | (((u >> 1) & 3) << 2);
    const int col = H * THALF + chs * 32 + 2 * i;
    unsigned short* vb = vtg + (size_t)bh * 9 * VGSTR + col;
#pragma unroll
    for (int d = 0; d < ND; d++)
        *(unsigned int*)&vb[d * VGSTR] = pkrtz(p0[d] * mz0, p1[d] * mz1);
    *(unsigned int*)&vb[8 * VGSTR] = pkrtz(mz0, mz1);   // ones row carries mask
}

// attn: UNCHANGED from R12 (frozen for attribution). One block = one (b,h) x
// one SIXTEENTH of query rows (128); 8 waves x one m-tile each; phased t;
// staging = coalesced uint4 copy; 16x16x16f16 scores, C-layout pi-packed into
// PV A-frag; ones-row -> denominator in O column 8.
__global__ __launch_bounds__(512) void attn_kernel(
        const unsigned short* __restrict__ qg,
        const unsigned short* __restrict__ vtg,
        unsigned short* __restrict__ mid) {            // f16 [B*S][NE]
    __shared__ unsigned short qhl[THALF * ND + 24];    // 16,432 B (+24: A-frag overread pad)
    __shared__ unsigned short vT[9 * VSTRIDE];         // 18,576 B
                                                       // total 35,008 B -> 4 blocks/CU

    const int bid = blockIdx.x;
    const int bh = bid >> 4;
    const int b = bh >> 4, h = bh & (NH - 1);
    const int msix = bid & 15;
    const int tid = threadIdx.x;

    const int wave = tid >> 6, lane = tid & 63;
    const int quad = lane >> 4, l15 = lane & 15;
    const int mbase = msix * 128 + wave * 16;

    if (tid < 24) qhl[THALF * ND + tid] = 0;   // pad (never contributes)

    // B operand (own m rows) from global qg: 16x16x16 B-frag = 4 f16, k=quad*4+j.
    // quads 0,1 real (k=0..7); quads 2,3 zero (kills the A garbage half).
    half4 hz4 = {0, 0, 0, 0};
    const unsigned short* qmrow = qg + ((size_t)bh * NS + mbase + l15) * ND
                                + (quad < 2 ? quad * 4 : 0);
    half4 bm0 = (quad < 2) ? *(const half4*)qmrow : hz4;

    const int vrow = (l15 < 9) ? l15 : 8;
    const unsigned short* vbase = &vT[vrow * VSTRIDE];

    f32x4 O0 = {0.f, 0.f, 0.f, 0.f};
    const f32x4 zc = {0.f, 0.f, 0.f, 0.f};

    for (int p = 0; p < 2; p++) {
        // ---- stage this t-half: pure copies ----
        {   // qhl: 1024 rows x 16B = 1024 uint4, contiguous
            const uint4* qs = (const uint4*)(qg + ((size_t)bh * NS + p * THALF) * ND);
            uint4* qd = (uint4*)qhl;
            qd[tid] = qs[tid];
            qd[tid + 512] = qs[tid + 512];
        }
        {   // vT: 9 rows x 1024 shorts = 1152 uint4
            const unsigned short* vs = vtg + (size_t)bh * 9 * VGSTR + p * THALF;
            for (int jj = tid; jj < 1152; jj += 512) {
                int d = jj >> 7, c = (jj & 127) << 3;
                *(uint4*)&vT[d * VSTRIDE + c] = *(const uint4*)&vs[d * VGSTR + c];
            }
        }
        __syncthreads();

        // ---- 32 chunks of this half; O keeps accumulating across phases ----
        for (int ch = 0; ch < NCH; ch++) {
            int tb = ch * 32;
            // A operand (q_t) b64: quads 0,1 = row halves (k 0..7); quads 2,3
            // read the next row (garbage) — zeroed by B.
            half4 at0 = *(const half4*)&qhl[(tb + l15) * ND + quad * 4];
            half4 at1 = *(const half4*)&qhl[(tb + 16 + l15) * ND + quad * 4];
            half8 vf  = *(const half8*)&vbase[tb + quad * 8];

            // S^T tiles (16x16x16; C-layout identical to x32): rows t, cols m=l15
            f32x4 s00 = __builtin_amdgcn_mfma_f32_16x16x16f16(at0, bm0, zc, 0, 0, 0);
            f32x4 s10 = __builtin_amdgcn_mfma_f32_16x16x16f16(at1, bm0, zc, 0, 0, 0);

            // exp2 + in-lane pack -> PV A-frag (k-order = pi)
            half8 pA0 = mk_half8(
                pkrtz(__builtin_amdgcn_exp2f(s00[0]), __builtin_amdgcn_exp2f(s00[1])),
                pkrtz(__builtin_amdgcn_exp2f(s00[2]), __builtin_amdgcn_exp2f(s00[3])),
                pkrtz(__builtin_amdgcn_exp2f(s10[0]), __builtin_amdgcn_exp2f(s10[1])),
                pkrtz(__builtin_amdgcn_exp2f(s10[2]), __builtin_amdgcn_exp2f(s10[3])));

            O0 = __builtin_amdgcn_mfma_f32_16x16x32_f16(pA0, vf, O0, 0, 0, 0);
        }
        __syncthreads();   // all waves done reading before re-stage
    }

    // ---- epilogue: l = column 8 of O; normalize; f16 store ----
#pragma unroll
    for (int r = 0; r < 4; r++) {
        float lsum = __shfl(O0[r], (lane & 48) | 8, 64);
        float v = O0[r] / lsum;
        if (l15 < ND) {
            int m = mbase + quad * 4 + r;
            mid[(size_t)(b * NS + m) * NE + h * ND + l15] = f2h(v);
        }
    }
}

// R13 proj: LDS-free. Old proj was 1 block/CU x 4 waves = 1 wave/SIMD with a
// 64 KB w-staging prologue -> L2 latency fully exposed (~11 us for ~1 us of
// traffic). Now: w pre-converted once (wf16, 32 KB, L1/L2-hot); each wave
// loads A (16 mid rows) + B (16 wf16 rows) fragments straight from global,
// 4 MFMAs, coalesced stores. Grid 512 x 512 thr, no LDS, tiny VGPR.
__global__ __launch_bounds__(512) void proj_kernel(
        const unsigned short* __restrict__ mid,
        const unsigned short* __restrict__ wf16,
        float* __restrict__ out) {
    const int rb = blockIdx.x * 16;
    const int tid = threadIdx.x;
    const int wavei = tid >> 6, lane = tid & 63;
    const int quad = lane >> 4, l15 = lane & 15;
    const int n0 = wavei * 16;

    f32x4 acc = {0.f, 0.f, 0.f, 0.f};
#pragma unroll
    for (int kt = 0; kt < 4; kt++) {
        half8 af = *(const half8*)&mid[(size_t)(rb + l15) * NE + kt * 32 + quad * 8];
        half8 bf = *(const half8*)&wf16[(n0 + l15) * NE + kt * 32 + quad * 8];
        acc = __builtin_amdgcn_mfma_f32_16x16x32_f16(af, bf, acc, 0, 0, 0);
    }
#pragma unroll
    for (int r = 0; r < 4; r++)
        out[(size_t)(rb + quad * 4 + r) * NE + n0 + l15] = acc[r];
}

extern "C" void kernel_launch(void* const* d_in, const int* in_sizes, int n_in,
                              void* d_out, int out_size, void* d_ws, size_t ws_size,
                              hipStream_t stream) {
    const float* x     = (const float*)d_in[0];
    const float* theta = (const float*)d_in[1];
    const float* w_out = (const float*)d_in[2];
    const int*   mask  = (const int*)d_in[3];
    float* out = (float*)d_out;

    // workspace: mid (2 MB) | qg (2 MB) | vtg (~2.37 MB) | wf16 (32 KB)
    unsigned short* mid16 = (unsigned short*)d_ws;
    unsigned short* qg   = mid16 + (size_t)NB * NS * NE;           // 1,048,576 shorts
    unsigned short* vtg  = qg + (size_t)NB * NH * NS * ND;         // 1,048,576 shorts
    unsigned short* wf16 = vtg + (size_t)NB * NH * 9 * VGSTR;      // 1,184,256 shorts

    qgen_kernel<<<NB * NH * NS / 2 / 256, 256, 0, stream>>>(x, theta, mask, w_out,
                                                            qg, vtg, wf16);
    attn_kernel<<<NB * NH * 16, 512, 0, stream>>>(qg, vtg, mid16);
    proj_kernel<<<NB * NS / 16, 512, 0, stream>>>(mid16, wf16, out);
}